// Round 4
// baseline (259.067 us; speedup 1.0000x reference)
//
#include <hip/hip_runtime.h>

// VectorQuantizer: M=32768 rows, N=8192 codes, D=256, fp32.
// Outputs flat fp32: [z_out 8388608][loss 1][idx 32768]
// idx = argmax zf.cb (l2-normalized); z_out = cb[idx]; loss = 1.25*mean((cb[idx]-zf)^2)
//
// R11: rescore occupancy + latency hardening. (a) __launch_bounds__(256,4)
// caps VGPR at 128 (clean HW step) -- rescore is a latency-chain kernel and
// the fp64 tie path was suspected of pushing regs past the 4-wave/SIMD step.
// (b) ns==1 wave-uniform fast path: a unique within-margin survivor is
// provably the exact argmin (prune keeps all possible winners; ties never
// pruned) -- skips dot/dmin/near-tie machinery in the common case.
// (c) cand load hoisted to overlap the x-row load. Scan untouched (R10:
// 123.6us, MfmaUtil 51%, reg-capped at 2 waves/SIMD -- structural limit).

#define M_ROWS 32768
#define N_CODES 8192
#define DIM 256
#define NT 64             // 32-code tiles per quarter (2048 codes)
#define BUF_B 16384       // 32 code rows * 512B

typedef short v8s __attribute__((ext_vector_type(8)));
typedef _Float16 v8h __attribute__((ext_vector_type(8)));
typedef float v4f __attribute__((ext_vector_type(4)));
typedef unsigned int uint;
typedef unsigned long long ull;

__device__ __forceinline__ unsigned short f2h(float f) {
    union { _Float16 h; unsigned short u; } c;
    c.h = (_Float16)f;                       // v_cvt_f16_f32, RTNE
    return c.u;
}
__device__ __forceinline__ uint umax2(uint a, uint b) { return a > b ? a : b; }
__device__ __forceinline__ uint umax3(uint a, uint b, uint c) {
    uint d; asm("v_max3_u32 %0, %1, %2, %3" : "=v"(d) : "v"(a), "v"(b), "v"(c)); return d;
}
__device__ __forceinline__ uint umed3(uint a, uint b, uint c) {
    uint d; asm("v_med3_u32 %0, %1, %2, %3" : "=v"(d) : "v"(a), "v"(b), "v"(c)); return d;
}
__device__ __forceinline__ int swz(int u, int r) {    // 16B-unit XOR swizzle (involution)
    return (u & 24) | ((u ^ r) & 7);
}
__device__ __forceinline__ void dma16(const void* g, void* l) {
    __builtin_amdgcn_global_load_lds(
        (const __attribute__((address_space(1))) unsigned int*)g,
        (__attribute__((address_space(3))) unsigned int*)l, 16, 0, 0);
}

// One wave per row; fused: blocks [0, N_CODES/4) normalize the codebook
// (fp32 out + PRE-SWIZZLED fp16 image for scan's global_load_lds), the rest
// normalize x rows (linear fp16). Swizzled image layout:
//   byte = r*512 + swz(lane>>1, r&31)*16 + (lane&1)*8
__global__ __launch_bounds__(256) void normalize_kernel(
        const float* __restrict__ emb, const float* __restrict__ x,
        float* __restrict__ cb, unsigned short* __restrict__ cbh,
        unsigned short* __restrict__ zfh) {
    int wave = threadIdx.x >> 6, lane = threadIdx.x & 63;
    int rg = blockIdx.x * 4 + wave;
    bool is_cb = rg < N_CODES;
    int r = is_cb ? rg : rg - N_CODES;
    const float* src = is_cb ? emb : x;
    float4 v = *(const float4*)(src + (size_t)r * DIM + lane * 4);
    float ss = v.x * v.x + v.y * v.y + v.z * v.z + v.w * v.w;
    #pragma unroll
    for (int o = 32; o; o >>= 1) ss += __shfl_xor(ss, o);
    float rinv = 1.0f / fmaxf(sqrtf(ss), 1e-12f);
    float4 o4; o4.x = v.x * rinv; o4.y = v.y * rinv; o4.z = v.z * rinv; o4.w = v.w * rinv;
    ushort4 b; b.x = f2h(o4.x); b.y = f2h(o4.y); b.z = f2h(o4.z); b.w = f2h(o4.w);
    if (is_cb) {
        *(float4*)(cb + (size_t)r * DIM + lane * 4) = o4;
        int rr = r & 31;
        size_t off = (size_t)r * 512
                   + (size_t)swz(lane >> 1, rr) * 16
                   + (size_t)(lane & 1) * 8;
        *(ushort4*)((char*)cbh + off) = b;
    } else {
        *(ushort4*)(zfh + (size_t)r * DIM + lane * 4) = b;
    }
}

// Scan: block = 256 rows x one quarter (2048 codes). Wave w owns rows
// [w*64, w*64+64) as 4 MFMA row-groups sharing each B fragment. 32-code tiles:
// 16 ds_read_b128 -> 64 MFMA per tile per wave. Staging: global_load_lds
// width=16 from pre-swizzled cbh into linear quad-buffer. One raw s_barrier
// per tile; counted vmcnt(8) keeps 2 tiles of DMA in flight across barriers.
// Race-freedom: issue(t+3) into buf[(t+3)&3]=buf[(t-1)&3] happens after
// barrier(t), which implies ALL waves finished compute(t-1) on that buffer.
// Top-2 keys per (row, residue16): key = fp32bits(score+2) & ~0x1FF | tile9.
__global__ __launch_bounds__(256, 2) void scan_kernel(
        const unsigned short* __restrict__ zfh,
        const unsigned short* __restrict__ cbh,
        uint* __restrict__ cand) {   // [row][128] = [row][4quarter][16res][2]
    __shared__ __align__(16) char lds[4 * BUF_B];
    int tid = threadIdx.x, w = tid >> 6, lane = tid & 63;
    int m = lane & 15, g = lane >> 4;
    int rb = blockIdx.x >> 2, quarter = blockIdx.x & 3;
    int r0 = rb * 256 + w * 64;
    const v4f C2 = {2.f, 2.f, 2.f, 2.f};

    // A fragments: A[m][k], k = c*32 + g*8 + j ; 4 row-groups of 16
    v8h a[4][8];
    #pragma unroll
    for (int h = 0; h < 4; ++h) {
        const unsigned short* ap = zfh + (size_t)(r0 + h * 16 + m) * DIM + g * 8;
        #pragma unroll
        for (int c = 0; c < 8; ++c) a[h][c] = *(const v8h*)(ap + c * 32);
    }
    // Pin a-loads before DMA issues so the manual vmcnt counting stays FIFO-sane.
    asm volatile("" ::: "memory");

    const char* cb_base = (const char*)cbh + ((size_t)quarter << 20);
    int wq = 4 * w;   // this wave's 4 chunks: q = wq..wq+3, 1KB each

    // ds_read offsets per K-chunk c (sub-tile 0; sub-tile 1 = +8192)
    int roff[8];
    #pragma unroll
    for (int c = 0; c < 8; ++c)
        roff[c] = m * 512 + swz(4 * c + g, m) * 16;

    // DMA prologue: tiles 0..2 into buf 0..2 (12 loads/wave outstanding)
    #pragma unroll
    for (int tt = 0; tt < 3; ++tt) {
        const char* gsrc = cb_base + (size_t)tt * BUF_B + wq * 1024 + lane * 16;
        char* lb = lds + (tt & 3) * BUF_B + wq * 1024;
        #pragma unroll
        for (int i = 0; i < 4; ++i) dma16(gsrc + i * 1024, lb + i * 1024);
    }

    uint top1[16], top2[16];
    #pragma unroll
    for (int i = 0; i < 16; ++i) { top1[i] = 0u; top2[i] = 0u; }

    for (int t = 0; t < NT; ++t) {
        // Counted wait: outstanding = tiles {t, t+1, t+2} (12) -> leave 8 => tile t landed.
        if (t < NT - 2) asm volatile("s_waitcnt vmcnt(8)" ::: "memory");
        else            asm volatile("s_waitcnt vmcnt(0)" ::: "memory");
        __builtin_amdgcn_s_barrier();    // all waves' tile-t chunks visible
        if (t + 3 < NT) {                // prefetch 3 ahead (safe: see header)
            const char* gsrc = cb_base + (size_t)(t + 3) * BUF_B + wq * 1024 + lane * 16;
            char* lb = lds + ((t + 3) & 3) * BUF_B + wq * 1024;
            #pragma unroll
            for (int i = 0; i < 4; ++i) dma16(gsrc + i * 1024, lb + i * 1024);
        }
        const char* cbuf = lds + (t & 3) * BUF_B;
        v4f acc[2][4];
        __builtin_amdgcn_s_setprio(1);
        #pragma unroll
        for (int s2 = 0; s2 < 2; ++s2) {
            #pragma unroll
            for (int c = 0; c < 8; ++c) {
                v8h b = *(const v8h*)(cbuf + s2 * 8192 + roff[c]);
                #pragma unroll
                for (int h = 0; h < 4; ++h) {
                    v4f cin = (c == 0) ? C2 : acc[s2][h];   // C=const: no init movs
                    acc[s2][h] = __builtin_amdgcn_mfma_f32_16x16x32_f16(a[h][c], b, cin, 0, 0, 0);
                }
            }
        }
        __builtin_amdgcn_s_setprio(0);
        uint gt0 = (uint)(quarter * 128 + 2 * t);       // 9-bit global tile ids
        uint gt1 = gt0 + 1u;
        #pragma unroll
        for (int i = 0; i < 16; ++i) {
            float s0 = acc[0][i >> 2][i & 3];           // in [1,3]: bits sortable
            float s1 = acc[1][i >> 2][i & 3];
            uint k0 = (__float_as_uint(s0) & 0xFFFFFE00u) | gt0;  // v_and_or_b32
            uint k1 = (__float_as_uint(s1) & 0xFFFFFE00u) | gt1;
            uint old1 = top1[i];
            // stream top-2: top2' = max(top2, med3(old1,k0,k1)); top1' = max3
            top1[i] = umax3(old1, k0, k1);
            top2[i] = umax2(top2[i], umed3(old1, k0, k1));
        }
    }

    // C/D layout: row = g*4 + q, col(residue) = m
    #pragma unroll
    for (int i = 0; i < 16; ++i) {
        int h = i >> 2, q = i & 3;
        int row = r0 + h * 16 + g * 4 + q;
        uint2 v; v.x = top1[i]; v.y = top2[i];
        *(uint2*)(cand + (size_t)row * 128 + (quarter * 16 + m) * 2) = v;
    }
}

// One wave per row. Prune 128 candidates at margin 0.008 (worst-case fp16 key
// skew ~0.0032), compact survivors via ballot-prefix into wave-private LDS.
// ns==1 (common case): the unique within-margin survivor is provably the
// exact argmin -> skip all scoring. Else survivors rescored serially with
// full-wave coalesced row reads + shfl tree-sum; fp64 wave-rescore only for
// fp32 near-ties (2e-4 >> fp32 tree-sum error). First-index tie-break.
__global__ __launch_bounds__(256, 4) void rescore_kernel(
        const float* __restrict__ x, const float* __restrict__ cb,
        const uint* __restrict__ cand, float* __restrict__ out,
        float* __restrict__ out_idx, double* __restrict__ lossp) {
    __shared__ int s_surv[4][128];
    int w = threadIdx.x >> 6, lane = threadIdx.x & 63;
    int r = blockIdx.x * 4 + w;
    // Issue both independent HBM loads back-to-back before any reduction.
    float4 xv = *(const float4*)(x + (size_t)r * DIM + lane * 4);
    uint2 kk = *(const uint2*)(cand + (size_t)r * 128 + lane * 2);

    float ss = xv.x * xv.x + xv.y * xv.y + xv.z * xv.z + xv.w * xv.w;
    #pragma unroll
    for (int o = 32; o; o >>= 1) ss += __shfl_xor(ss, o);
    float rinv = 1.0f / fmaxf(sqrtf(ss), 1e-12f);
    float4 z4; z4.x = xv.x * rinv; z4.y = xv.y * rinv; z4.z = xv.z * rinv; z4.w = xv.w * rinv;

    float kf0 = __uint_as_float(kk.x & 0xFFFFFE00u);
    float kf1 = __uint_as_float(kk.y & 0xFFFFFE00u);
    float kmax = fmaxf(kf0, kf1);
    #pragma unroll
    for (int o = 32; o; o >>= 1) kmax = fmaxf(kmax, __shfl_xor(kmax, o));
    float thr = kmax - 0.008f;
    bool p0 = kf0 >= thr, p1 = kf1 >= thr;
    ull m0 = __ballot(p0), m1 = __ballot(p1);
    ull lt = (1ull << lane) - 1ull;
    int ns0 = __popcll(m0);
    int ns = ns0 + __popcll(m1);
    int code0 = (int)(kk.x & 0x1FFu) * 16 + (lane & 15);
    int code1 = (int)(kk.y & 0x1FFu) * 16 + (lane & 15);
    if (p0) s_surv[w][__popcll(m0 & lt)] = code0;
    if (p1) s_surv[w][ns0 + __popcll(m1 & lt)] = code1;
    // wave-private LDS: same-wave DS ops execute in order; no barrier needed.

    int bestj;
    if (ns == 1) {
        // Unique within-margin survivor: margin covers worst-case fp16 skew,
        // so every code that could possibly win survives; ties are never
        // pruned (equal true scores => keys within 2*skew < margin). Exact.
        bestj = s_surv[w][0];
    } else {
        float d1 = 3.0e38f; int jj = 0x7fffffff;
        int nsl = ns < 64 ? ns : 64;
        for (int s = 0; s < nsl; ++s) {
            int j = s_surv[w][s];
            float4 c4 = *(const float4*)(cb + (size_t)j * DIM + lane * 4);
            float d = c4.x * (c4.x - 2.f * z4.x) + c4.y * (c4.y - 2.f * z4.y)
                    + c4.z * (c4.z - 2.f * z4.z) + c4.w * (c4.w - 2.f * z4.w);
            #pragma unroll
            for (int o = 32; o; o >>= 1) d += __shfl_xor(d, o);
            if (lane == s) { d1 = d; jj = j; }
        }
        if (ns > 64) {   // effectively never for this data; correctness fallback
            float d2 = 3.0e38f; int jj2 = 0x7fffffff;
            for (int s = 64; s < ns; ++s) {
                int j = s_surv[w][s];
                float4 c4 = *(const float4*)(cb + (size_t)j * DIM + lane * 4);
                float d = c4.x * (c4.x - 2.f * z4.x) + c4.y * (c4.y - 2.f * z4.y)
                        + c4.z * (c4.z - 2.f * z4.z) + c4.w * (c4.w - 2.f * z4.w);
                #pragma unroll
                for (int o = 32; o; o >>= 1) d += __shfl_xor(d, o);
                if (lane == s - 64) { d2 = d; jj2 = j; }
            }
            if (d2 < d1 || (d2 == d1 && jj2 < jj)) { d1 = d2; jj = jj2; }
        }
        float dmin = d1;
        #pragma unroll
        for (int o = 32; o; o >>= 1) dmin = fminf(dmin, __shfl_xor(dmin, o));
        ull nearm = __ballot(d1 <= dmin + 2e-4f);
        if (__popcll(nearm) == 1) {
            bestj = __shfl(jj, (int)__builtin_ctzll(nearm));   // provably exact
        } else {
            double bestd = 1e300; bestj = 0x7fffffff;
            while (nearm) {
                int b = (int)__builtin_ctzll(nearm); nearm &= nearm - 1;
                int jc = __shfl(jj, b);
                float4 c4 = *(const float4*)(cb + (size_t)jc * DIM + lane * 4);
                double p = (double)c4.x * ((double)c4.x - 2.0 * (double)z4.x)
                         + (double)c4.y * ((double)c4.y - 2.0 * (double)z4.y)
                         + (double)c4.z * ((double)c4.z - 2.0 * (double)z4.z)
                         + (double)c4.w * ((double)c4.w - 2.0 * (double)z4.w);
                #pragma unroll
                for (int o = 32; o; o >>= 1) p += __shfl_xor(p, o);
                if (p < bestd || (p == bestd && jc < bestj)) { bestd = p; bestj = jc; }
            }
        }
    }
    float4 c4 = *(const float4*)(cb + (size_t)bestj * DIM + lane * 4);
    *(float4*)(out + (size_t)r * DIM + lane * 4) = c4;
    double dx = (double)c4.x - (double)z4.x, dy = (double)c4.y - (double)z4.y;
    double dz = (double)c4.z - (double)z4.z, dw = (double)c4.w - (double)z4.w;
    double lp = dx * dx + dy * dy + dz * dz + dw * dw;
    #pragma unroll
    for (int o = 32; o; o >>= 1) lp += __shfl_xor(lp, o);
    if (lane == 0) { lossp[r] = lp; out_idx[r] = (float)bestj; }
}

__global__ __launch_bounds__(256) void loss_kernel(
        const double* __restrict__ lossp, float* __restrict__ out) {
    __shared__ double sm[256];
    double s = 0.0;
    for (int i = threadIdx.x; i < M_ROWS; i += 256) s += lossp[i];
    sm[threadIdx.x] = s;
    __syncthreads();
    for (int o = 128; o; o >>= 1) {
        if ((int)threadIdx.x < o) sm[threadIdx.x] += sm[threadIdx.x + o];
        __syncthreads();
    }
    if (threadIdx.x == 0)
        out[0] = (float)(sm[0] * (1.25 / (double)(M_ROWS * DIM)));  // (BETA+1)*mean
}

extern "C" void kernel_launch(void* const* d_in, const int* in_sizes, int n_in,
                              void* d_out, int out_size, void* d_ws, size_t ws_size,
                              hipStream_t stream) {
    const float* x   = (const float*)d_in[0];   // 32*1024*256
    const float* emb = (const float*)d_in[1];   // 8192*256
    float* out = (float*)d_out;
    char* ws = (char*)d_ws;

    float*          cb    = (float*)(ws);                          // 8 MB
    unsigned short* cbh   = (unsigned short*)(ws + (8u  << 20));   // 4 MB (swizzled fp16 image)
    unsigned short* zfh   = (unsigned short*)(ws + (12u << 20));   // 16 MB
    uint*           cand  = (uint*)(ws + (28u << 20));             // 16 MB
    double*         lossp = (double*)(ws + (44u << 20));           // 256 KB

    normalize_kernel<<<(N_CODES + M_ROWS) / 4, 256, 0, stream>>>(emb, x, cb, cbh, zfh);
    scan_kernel<<<512, 256, 0, stream>>>(zfh, cbh, cand);
    rescore_kernel<<<M_ROWS / 4, 256, 0, stream>>>(x, cb, cand,
                                                   out, out + ((size_t)M_ROWS * DIM + 1), lossp);
    loss_kernel<<<1, 256, 0, stream>>>(lossp, out + (size_t)M_ROWS * DIM);
}

// Round 5
// 232.043 us; speedup vs baseline: 1.1165x; 1.1165x over previous
//
#include <hip/hip_runtime.h>

// VectorQuantizer: M=32768 rows, N=8192 codes, D=256, fp32.
// Outputs flat fp32: [z_out 8388608][loss 1][idx 32768]
// idx = argmax zf.cb (l2-normalized); z_out = cb[idx]; loss = 1.25*mean((cb[idx]-zf)^2)
//
// R12: (a) loss reduction parallelized: 64 blocks x double2 loads + last-block
// final reduce via device atomic counter (old single-block version did 128
// serial 8B loads on one CU -- prime suspect for the hidden ~40us; top-5
// couldn't show it). Still 4 dispatches. (b) rescore: speculative cb-row
// prefetch -- argmax-key lane's code is known right after the kmax reduce;
// for ns==1 it provably equals bestj, removing the dependent 1KB load from
// the critical chain. Scan/normalize untouched (R10: scan 122us structural).

#define M_ROWS 32768
#define N_CODES 8192
#define DIM 256
#define NT 64             // 32-code tiles per quarter (2048 codes)
#define BUF_B 16384       // 32 code rows * 512B

typedef short v8s __attribute__((ext_vector_type(8)));
typedef _Float16 v8h __attribute__((ext_vector_type(8)));
typedef float v4f __attribute__((ext_vector_type(4)));
typedef unsigned int uint;
typedef unsigned long long ull;

__device__ __forceinline__ unsigned short f2h(float f) {
    union { _Float16 h; unsigned short u; } c;
    c.h = (_Float16)f;                       // v_cvt_f16_f32, RTNE
    return c.u;
}
__device__ __forceinline__ uint umax2(uint a, uint b) { return a > b ? a : b; }
__device__ __forceinline__ uint umax3(uint a, uint b, uint c) {
    uint d; asm("v_max3_u32 %0, %1, %2, %3" : "=v"(d) : "v"(a), "v"(b), "v"(c)); return d;
}
__device__ __forceinline__ uint umed3(uint a, uint b, uint c) {
    uint d; asm("v_med3_u32 %0, %1, %2, %3" : "=v"(d) : "v"(a), "v"(b), "v"(c)); return d;
}
__device__ __forceinline__ int swz(int u, int r) {    // 16B-unit XOR swizzle (involution)
    return (u & 24) | ((u ^ r) & 7);
}
__device__ __forceinline__ void dma16(const void* g, void* l) {
    __builtin_amdgcn_global_load_lds(
        (const __attribute__((address_space(1))) unsigned int*)g,
        (__attribute__((address_space(3))) unsigned int*)l, 16, 0, 0);
}

// One wave per row; fused: blocks [0, N_CODES/4) normalize the codebook
// (fp32 out + PRE-SWIZZLED fp16 image for scan's global_load_lds), the rest
// normalize x rows (linear fp16). Swizzled image layout:
//   byte = r*512 + swz(lane>>1, r&31)*16 + (lane&1)*8
// Also zeroes the loss last-block counter for this iteration.
__global__ __launch_bounds__(256) void normalize_kernel(
        const float* __restrict__ emb, const float* __restrict__ x,
        float* __restrict__ cb, unsigned short* __restrict__ cbh,
        unsigned short* __restrict__ zfh, uint* __restrict__ count) {
    if (blockIdx.x == 0 && threadIdx.x == 0) *count = 0u;
    int wave = threadIdx.x >> 6, lane = threadIdx.x & 63;
    int rg = blockIdx.x * 4 + wave;
    bool is_cb = rg < N_CODES;
    int r = is_cb ? rg : rg - N_CODES;
    const float* src = is_cb ? emb : x;
    float4 v = *(const float4*)(src + (size_t)r * DIM + lane * 4);
    float ss = v.x * v.x + v.y * v.y + v.z * v.z + v.w * v.w;
    #pragma unroll
    for (int o = 32; o; o >>= 1) ss += __shfl_xor(ss, o);
    float rinv = 1.0f / fmaxf(sqrtf(ss), 1e-12f);
    float4 o4; o4.x = v.x * rinv; o4.y = v.y * rinv; o4.z = v.z * rinv; o4.w = v.w * rinv;
    ushort4 b; b.x = f2h(o4.x); b.y = f2h(o4.y); b.z = f2h(o4.z); b.w = f2h(o4.w);
    if (is_cb) {
        *(float4*)(cb + (size_t)r * DIM + lane * 4) = o4;
        int rr = r & 31;
        size_t off = (size_t)r * 512
                   + (size_t)swz(lane >> 1, rr) * 16
                   + (size_t)(lane & 1) * 8;
        *(ushort4*)((char*)cbh + off) = b;
    } else {
        *(ushort4*)(zfh + (size_t)r * DIM + lane * 4) = b;
    }
}

// Scan: block = 256 rows x one quarter (2048 codes). Wave w owns rows
// [w*64, w*64+64) as 4 MFMA row-groups sharing each B fragment. 32-code tiles:
// 16 ds_read_b128 -> 64 MFMA per tile per wave. Staging: global_load_lds
// width=16 from pre-swizzled cbh into linear quad-buffer. One raw s_barrier
// per tile; counted vmcnt(8) keeps 2 tiles of DMA in flight across barriers.
// Race-freedom: issue(t+3) into buf[(t+3)&3]=buf[(t-1)&3] happens after
// barrier(t), which implies ALL waves finished compute(t-1) on that buffer.
// Top-2 keys per (row, residue16): key = fp32bits(score+2) & ~0x1FF | tile9.
__global__ __launch_bounds__(256, 2) void scan_kernel(
        const unsigned short* __restrict__ zfh,
        const unsigned short* __restrict__ cbh,
        uint* __restrict__ cand) {   // [row][128] = [row][4quarter][16res][2]
    __shared__ __align__(16) char lds[4 * BUF_B];
    int tid = threadIdx.x, w = tid >> 6, lane = tid & 63;
    int m = lane & 15, g = lane >> 4;
    int rb = blockIdx.x >> 2, quarter = blockIdx.x & 3;
    int r0 = rb * 256 + w * 64;
    const v4f C2 = {2.f, 2.f, 2.f, 2.f};

    // A fragments: A[m][k], k = c*32 + g*8 + j ; 4 row-groups of 16
    v8h a[4][8];
    #pragma unroll
    for (int h = 0; h < 4; ++h) {
        const unsigned short* ap = zfh + (size_t)(r0 + h * 16 + m) * DIM + g * 8;
        #pragma unroll
        for (int c = 0; c < 8; ++c) a[h][c] = *(const v8h*)(ap + c * 32);
    }
    // Pin a-loads before DMA issues so the manual vmcnt counting stays FIFO-sane.
    asm volatile("" ::: "memory");

    const char* cb_base = (const char*)cbh + ((size_t)quarter << 20);
    int wq = 4 * w;   // this wave's 4 chunks: q = wq..wq+3, 1KB each

    // ds_read offsets per K-chunk c (sub-tile 0; sub-tile 1 = +8192)
    int roff[8];
    #pragma unroll
    for (int c = 0; c < 8; ++c)
        roff[c] = m * 512 + swz(4 * c + g, m) * 16;

    // DMA prologue: tiles 0..2 into buf 0..2 (12 loads/wave outstanding)
    #pragma unroll
    for (int tt = 0; tt < 3; ++tt) {
        const char* gsrc = cb_base + (size_t)tt * BUF_B + wq * 1024 + lane * 16;
        char* lb = lds + (tt & 3) * BUF_B + wq * 1024;
        #pragma unroll
        for (int i = 0; i < 4; ++i) dma16(gsrc + i * 1024, lb + i * 1024);
    }

    uint top1[16], top2[16];
    #pragma unroll
    for (int i = 0; i < 16; ++i) { top1[i] = 0u; top2[i] = 0u; }

    for (int t = 0; t < NT; ++t) {
        // Counted wait: outstanding = tiles {t, t+1, t+2} (12) -> leave 8 => tile t landed.
        if (t < NT - 2) asm volatile("s_waitcnt vmcnt(8)" ::: "memory");
        else            asm volatile("s_waitcnt vmcnt(0)" ::: "memory");
        __builtin_amdgcn_s_barrier();    // all waves' tile-t chunks visible
        if (t + 3 < NT) {                // prefetch 3 ahead (safe: see header)
            const char* gsrc = cb_base + (size_t)(t + 3) * BUF_B + wq * 1024 + lane * 16;
            char* lb = lds + ((t + 3) & 3) * BUF_B + wq * 1024;
            #pragma unroll
            for (int i = 0; i < 4; ++i) dma16(gsrc + i * 1024, lb + i * 1024);
        }
        const char* cbuf = lds + (t & 3) * BUF_B;
        v4f acc[2][4];
        __builtin_amdgcn_s_setprio(1);
        #pragma unroll
        for (int s2 = 0; s2 < 2; ++s2) {
            #pragma unroll
            for (int c = 0; c < 8; ++c) {
                v8h b = *(const v8h*)(cbuf + s2 * 8192 + roff[c]);
                #pragma unroll
                for (int h = 0; h < 4; ++h) {
                    v4f cin = (c == 0) ? C2 : acc[s2][h];   // C=const: no init movs
                    acc[s2][h] = __builtin_amdgcn_mfma_f32_16x16x32_f16(a[h][c], b, cin, 0, 0, 0);
                }
            }
        }
        __builtin_amdgcn_s_setprio(0);
        uint gt0 = (uint)(quarter * 128 + 2 * t);       // 9-bit global tile ids
        uint gt1 = gt0 + 1u;
        #pragma unroll
        for (int i = 0; i < 16; ++i) {
            float s0 = acc[0][i >> 2][i & 3];           // in [1,3]: bits sortable
            float s1 = acc[1][i >> 2][i & 3];
            uint k0 = (__float_as_uint(s0) & 0xFFFFFE00u) | gt0;  // v_and_or_b32
            uint k1 = (__float_as_uint(s1) & 0xFFFFFE00u) | gt1;
            uint old1 = top1[i];
            // stream top-2: top2' = max(top2, med3(old1,k0,k1)); top1' = max3
            top1[i] = umax3(old1, k0, k1);
            top2[i] = umax2(top2[i], umed3(old1, k0, k1));
        }
    }

    // C/D layout: row = g*4 + q, col(residue) = m
    #pragma unroll
    for (int i = 0; i < 16; ++i) {
        int h = i >> 2, q = i & 3;
        int row = r0 + h * 16 + g * 4 + q;
        uint2 v; v.x = top1[i]; v.y = top2[i];
        *(uint2*)(cand + (size_t)row * 128 + (quarter * 16 + m) * 2) = v;
    }
}

// One wave per row. Prune 128 candidates at margin 0.008 (worst-case fp16 key
// skew ~0.0032), compact survivors via ballot-prefix into wave-private LDS.
// Speculative prefetch: the argmax-key lane's code is known right after the
// kmax reduce; its cb row is loaded immediately. ns==1 => spec IS the exact
// argmin (unique within-margin survivor; ties never pruned) -- no dependent
// tail load. Else survivors rescored with full-wave coalesced rows + shfl
// tree-sum; fp64 wave-rescore only for fp32 near-ties. First-index tie-break.
__global__ __launch_bounds__(256, 4) void rescore_kernel(
        const float* __restrict__ x, const float* __restrict__ cb,
        const uint* __restrict__ cand, float* __restrict__ out,
        float* __restrict__ out_idx, double* __restrict__ lossp) {
    __shared__ int s_surv[4][128];
    int w = threadIdx.x >> 6, lane = threadIdx.x & 63;
    int r = blockIdx.x * 4 + w;
    // Issue both independent HBM loads back-to-back before any reduction.
    float4 xv = *(const float4*)(x + (size_t)r * DIM + lane * 4);
    uint2 kk = *(const uint2*)(cand + (size_t)r * 128 + lane * 2);

    float ss = xv.x * xv.x + xv.y * xv.y + xv.z * xv.z + xv.w * xv.w;
    #pragma unroll
    for (int o = 32; o; o >>= 1) ss += __shfl_xor(ss, o);
    float rinv = 1.0f / fmaxf(sqrtf(ss), 1e-12f);
    float4 z4; z4.x = xv.x * rinv; z4.y = xv.y * rinv; z4.z = xv.z * rinv; z4.w = xv.w * rinv;

    float kf0 = __uint_as_float(kk.x & 0xFFFFFE00u);
    float kf1 = __uint_as_float(kk.y & 0xFFFFFE00u);
    int code0 = (int)(kk.x & 0x1FFu) * 16 + (lane & 15);
    int code1 = (int)(kk.y & 0x1FFu) * 16 + (lane & 15);
    float mykey = fmaxf(kf0, kf1);
    int mycode = (kf0 >= kf1) ? code0 : code1;
    float kmax = mykey;
    #pragma unroll
    for (int o = 32; o; o >>= 1) kmax = fmaxf(kmax, __shfl_xor(kmax, o));
    // Speculative winner: first lane holding the max key. Unique when ns==1.
    ull mm = __ballot(mykey == kmax);
    int spec = __shfl(mycode, (int)__builtin_ctzll(mm));
    float4 cspec = *(const float4*)(cb + (size_t)spec * DIM + lane * 4);

    float thr = kmax - 0.008f;
    bool p0 = kf0 >= thr, p1 = kf1 >= thr;
    ull m0 = __ballot(p0), m1 = __ballot(p1);
    ull lt = (1ull << lane) - 1ull;
    int ns0 = __popcll(m0);
    int ns = ns0 + __popcll(m1);
    if (p0) s_surv[w][__popcll(m0 & lt)] = code0;
    if (p1) s_surv[w][ns0 + __popcll(m1 & lt)] = code1;
    // wave-private LDS: same-wave DS ops execute in order; no barrier needed.

    int bestj;
    if (ns == 1) {
        // Unique within-margin survivor = the kmax key's owner = spec.
        // Margin covers worst-case fp16 skew, so every possible winner
        // survives; ties are never pruned. Exact.
        bestj = spec;
    } else {
        float d1 = 3.0e38f; int jj = 0x7fffffff;
        int nsl = ns < 64 ? ns : 64;
        for (int s = 0; s < nsl; ++s) {
            int j = s_surv[w][s];
            float4 c4 = *(const float4*)(cb + (size_t)j * DIM + lane * 4);
            float d = c4.x * (c4.x - 2.f * z4.x) + c4.y * (c4.y - 2.f * z4.y)
                    + c4.z * (c4.z - 2.f * z4.z) + c4.w * (c4.w - 2.f * z4.w);
            #pragma unroll
            for (int o = 32; o; o >>= 1) d += __shfl_xor(d, o);
            if (lane == s) { d1 = d; jj = j; }
        }
        if (ns > 64) {   // effectively never for this data; correctness fallback
            float d2 = 3.0e38f; int jj2 = 0x7fffffff;
            for (int s = 64; s < ns; ++s) {
                int j = s_surv[w][s];
                float4 c4 = *(const float4*)(cb + (size_t)j * DIM + lane * 4);
                float d = c4.x * (c4.x - 2.f * z4.x) + c4.y * (c4.y - 2.f * z4.y)
                        + c4.z * (c4.z - 2.f * z4.z) + c4.w * (c4.w - 2.f * z4.w);
                #pragma unroll
                for (int o = 32; o; o >>= 1) d += __shfl_xor(d, o);
                if (lane == s - 64) { d2 = d; jj2 = j; }
            }
            if (d2 < d1 || (d2 == d1 && jj2 < jj)) { d1 = d2; jj = jj2; }
        }
        float dmin = d1;
        #pragma unroll
        for (int o = 32; o; o >>= 1) dmin = fminf(dmin, __shfl_xor(dmin, o));
        ull nearm = __ballot(d1 <= dmin + 2e-4f);
        if (__popcll(nearm) == 1) {
            bestj = __shfl(jj, (int)__builtin_ctzll(nearm));   // provably exact
        } else {
            double bestd = 1e300; bestj = 0x7fffffff;
            while (nearm) {
                int b = (int)__builtin_ctzll(nearm); nearm &= nearm - 1;
                int jc = __shfl(jj, b);
                float4 c4 = *(const float4*)(cb + (size_t)jc * DIM + lane * 4);
                double p = (double)c4.x * ((double)c4.x - 2.0 * (double)z4.x)
                         + (double)c4.y * ((double)c4.y - 2.0 * (double)z4.y)
                         + (double)c4.z * ((double)c4.z - 2.0 * (double)z4.z)
                         + (double)c4.w * ((double)c4.w - 2.0 * (double)z4.w);
                #pragma unroll
                for (int o = 32; o; o >>= 1) p += __shfl_xor(p, o);
                if (p < bestd || (p == bestd && jc < bestj)) { bestd = p; bestj = jc; }
            }
        }
    }
    float4 c4;
    if (bestj == spec) c4 = cspec;    // common path: already in registers
    else c4 = *(const float4*)(cb + (size_t)bestj * DIM + lane * 4);
    *(float4*)(out + (size_t)r * DIM + lane * 4) = c4;
    double dx = (double)c4.x - (double)z4.x, dy = (double)c4.y - (double)z4.y;
    double dz = (double)c4.z - (double)z4.z, dw = (double)c4.w - (double)z4.w;
    double lp = dx * dx + dy * dy + dz * dz + dw * dw;
    #pragma unroll
    for (int o = 32; o; o >>= 1) lp += __shfl_xor(lp, o);
    if (lane == 0) { lossp[r] = lp; out_idx[r] = (float)bestj; }
}

// 64 blocks x 512 doubles (double2 per thread, fully parallel loads).
// Last-finishing block (device atomic counter) reduces the 64 partials and
// writes the scaled fp32 loss. Counter zeroed each iteration by normalize.
__global__ __launch_bounds__(256) void loss_kernel(
        const double* __restrict__ lossp, float* __restrict__ out,
        double* __restrict__ partial, uint* __restrict__ count) {
    __shared__ double sm[256];
    __shared__ int is_last;
    int b = blockIdx.x, tid = threadIdx.x;
    double2 v = *(const double2*)(lossp + (size_t)b * 512 + tid * 2);
    sm[tid] = v.x + v.y;
    __syncthreads();
    for (int o = 128; o; o >>= 1) {
        if (tid < o) sm[tid] += sm[tid + o];
        __syncthreads();
    }
    if (tid == 0) {
        partial[b] = sm[0];
        __threadfence();                       // partial visible before count
        uint old = atomicAdd(count, 1u);       // device-scope
        is_last = (old == 63u);
    }
    __syncthreads();
    if (is_last && tid < 64) {
        __threadfence();                       // acquire all partials
        double p = partial[tid];
        #pragma unroll
        for (int o = 32; o; o >>= 1) p += __shfl_xor(p, o);
        if (tid == 0)
            out[0] = (float)(p * (1.25 / (double)(M_ROWS * DIM)));  // (BETA+1)*mean
    }
}

extern "C" void kernel_launch(void* const* d_in, const int* in_sizes, int n_in,
                              void* d_out, int out_size, void* d_ws, size_t ws_size,
                              hipStream_t stream) {
    const float* x   = (const float*)d_in[0];   // 32*1024*256
    const float* emb = (const float*)d_in[1];   // 8192*256
    float* out = (float*)d_out;
    char* ws = (char*)d_ws;

    float*          cb    = (float*)(ws);                          // 8 MB
    unsigned short* cbh   = (unsigned short*)(ws + (8u  << 20));   // 4 MB (swizzled fp16 image)
    unsigned short* zfh   = (unsigned short*)(ws + (12u << 20));   // 16 MB
    uint*           cand  = (uint*)(ws + (28u << 20));             // 16 MB
    double*         lossp = (double*)(ws + (44u << 20));           // 256 KB
    double*         partial = (double*)(ws + (44u << 20) + (512u << 10)); // 512 B
    uint*           count = (uint*)(ws + (44u << 20) + (513u << 10));     // 4 B

    normalize_kernel<<<(N_CODES + M_ROWS) / 4, 256, 0, stream>>>(emb, x, cb, cbh, zfh, count);
    scan_kernel<<<512, 256, 0, stream>>>(zfh, cbh, cand);
    rescore_kernel<<<M_ROWS / 4, 256, 0, stream>>>(x, cb, cand,
                                                   out, out + ((size_t)M_ROWS * DIM + 1), lossp);
    loss_kernel<<<64, 256, 0, stream>>>(lossp, out + (size_t)M_ROWS * DIM, partial, count);
}